// Round 1
// baseline (190.219 us; speedup 1.0000x reference)
//
#include <hip/hip_runtime.h>
#include <math.h>

#define HIDDEN  512
#define EXPERTS 4

// One wave (64 lanes) per token. Lane l covers x positions {l*4..l*4+3} and
// {256+l*4..256+l*4+3}. Gate fragments live in registers across the
// grid-stride token loop (gate_w is only 4x512 floats).
__global__ __launch_bounds__(256, 4) void gating_kernel(
    const float* __restrict__ x,        // [T, 512]
    const float* __restrict__ gate_w,   // [4, 512]
    const float* __restrict__ gate_b,   // [4]
    float* __restrict__ out_sparse,     // [T, 4]
    float* __restrict__ out_idx,        // [T, 2]  (indices stored as float)
    float* __restrict__ out_logit,      // [T, 4]
    int T)
{
    const int lane   = threadIdx.x & 63;
    const int wave   = (int)((blockIdx.x * blockDim.x + threadIdx.x) >> 6);
    const int nwaves = (int)((gridDim.x * blockDim.x) >> 6);

    // Per-lane gate fragments: 4 experts x 8 floats = 32 VGPRs. Loaded once.
    float4 gw0[EXPERTS], gw1[EXPERTS];
#pragma unroll
    for (int e = 0; e < EXPERTS; ++e) {
        gw0[e] = *reinterpret_cast<const float4*>(gate_w + e * HIDDEN + lane * 4);
        gw1[e] = *reinterpret_cast<const float4*>(gate_w + e * HIDDEN + 256 + lane * 4);
    }
    const float b0 = gate_b[0], b1 = gate_b[1], b2 = gate_b[2], b3 = gate_b[3];

    for (int t = wave; t < T; t += nwaves) {
        const float* xt = x + (size_t)t * HIDDEN;
        const float4 xv0 = *reinterpret_cast<const float4*>(xt + lane * 4);
        const float4 xv1 = *reinterpret_cast<const float4*>(xt + 256 + lane * 4);

        float s[EXPERTS];
#pragma unroll
        for (int e = 0; e < EXPERTS; ++e) {
            s[e] = xv0.x * gw0[e].x + xv0.y * gw0[e].y + xv0.z * gw0[e].z + xv0.w * gw0[e].w
                 + xv1.x * gw1[e].x + xv1.y * gw1[e].y + xv1.z * gw1[e].z + xv1.w * gw1[e].w;
        }

        // Butterfly reduction over the full 64-lane wave; every lane ends with
        // the complete sums, so the top-2/softmax below is wave-uniform.
#pragma unroll
        for (int off = 32; off >= 1; off >>= 1) {
#pragma unroll
            for (int e = 0; e < EXPERTS; ++e)
                s[e] += __shfl_xor(s[e], off, 64);
        }

        const float l0 = s[0] + b0, l1 = s[1] + b1, l2 = s[2] + b2, l3 = s[3] + b3;
        const float l[4] = {l0, l1, l2, l3};

        // top-1: strict > keeps the lowest index on ties (matches lax.top_k)
        int i1 = 0; float m1 = l[0];
#pragma unroll
        for (int e = 1; e < 4; ++e) { if (l[e] > m1) { m1 = l[e]; i1 = e; } }
        // top-2 among the rest
        int i2 = -1; float m2 = -INFINITY;
#pragma unroll
        for (int e = 0; e < 4; ++e) { if (e != i1 && l[e] > m2) { m2 = l[e]; i2 = e; } }

        // softmax over {m1, m2} with -inf elsewhere
        const float e2  = expf(m2 - m1);
        const float inv = 1.0f / (1.0f + e2);
        const float p1  = inv, p2 = e2 * inv;

        float sp[4];
#pragma unroll
        for (int e = 0; e < 4; ++e)
            sp[e] = (e == i1) ? p1 : ((e == i2) ? p2 : 0.0f);

        if (lane == 0) {
            const float4 spv = {sp[0], sp[1], sp[2], sp[3]};
            *reinterpret_cast<float4*>(out_sparse + (size_t)t * 4) = spv;
            const float2 iv = {(float)i1, (float)i2};
            *reinterpret_cast<float2*>(out_idx + (size_t)t * 2) = iv;
            const float4 lv = {l0, l1, l2, l3};
            *reinterpret_cast<float4*>(out_logit + (size_t)t * 4) = lv;
        }
    }
}

extern "C" void kernel_launch(void* const* d_in, const int* in_sizes, int n_in,
                              void* d_out, int out_size, void* d_ws, size_t ws_size,
                              hipStream_t stream) {
    const float* x      = (const float*)d_in[0];
    const float* gate_w = (const float*)d_in[1];
    const float* gate_b = (const float*)d_in[2];

    const int T = in_sizes[0] / HIDDEN;   // 65536 for B=8, S=8192

    float* out_sparse = (float*)d_out;                       // T*4
    float* out_idx    = out_sparse + (size_t)T * EXPERTS;    // T*2
    float* out_logit  = out_idx    + (size_t)T * 2;          // T*4

    const dim3 block(256);
    const dim3 grid(1024);   // 4096 waves -> 16 tokens/wave grid-stride
    gating_kernel<<<grid, block, 0, stream>>>(x, gate_w, gate_b,
                                              out_sparse, out_idx, out_logit, T);
}